// Round 7
// baseline (32.657 us; speedup 1.0000x reference)
//
#include <hip/hip_runtime.h>
#include <math.h>

#define KNBR 20
#define BLK  256
#define GRP  32              // lanes per atom
#define APB  (BLK / GRP)     // 8 atoms per block

#define THETA_T  1.9106332362490186f   // 0.6081734479693927 * pi
#define INV_SIG  4.7746482927568605f   // 1 / (12 deg in rad)
#define PI_F     3.14159265358979323846f

// ---- K0: pack float3 positions into 16B-aligned float4 (1 gather = 1 line) --
__global__ __launch_bounds__(BLK)
void k_pack(const float* __restrict__ pos, float4* __restrict__ pos4, int N)
{
    const int n = blockIdx.x * BLK + threadIdx.x;
    if (n < N)
        pos4[n] = make_float4(pos[3*n], pos[3*n+1], pos[3*n+2], 0.f);
}

// ---- main kernel: round-5 structure, float4 gathers --------------------------
// q_l via the SH addition theorem: q_l = (1/nb)*sqrt(cn + 2*sum_{i<j} P_l(d_ij))
__global__ __launch_bounds__(BLK)
void op_kernel(const float4* __restrict__ pos4,
               const int*    __restrict__ aidx,
               const int*    __restrict__ nidx,
               const int*    __restrict__ vmsk,
               float*        __restrict__ out,
               int M)
{
    __shared__ float4 su[APB * KNBR];       // 2560 B
    const int tid  = threadIdx.x;
    const int r    = tid & (GRP - 1);       // lane within 32-lane group
    const int al   = tid / GRP;             // atom in block 0..7
    const int i    = blockIdx.x * APB + al;
    if (i >= M) return;
    const int half = (tid & 63) >> 5;       // which 32-half of the wave

    // center position (uniform within group -> broadcast load, 1 line)
    const int a = aidx[i];
    const float4 C = pos4[a];

    // lane r < 20 owns neighbor slot r
    int valid = 0, nj = 0;
    if (r < KNBR) {
        nj    = nidx[(size_t)i * KNBR + r];
        valid = vmsk[(size_t)i * KNBR + r] != 0;
    }
    const unsigned long long bal = __ballot(valid != 0);
    const unsigned int b32 = (unsigned int)(bal >> (half * 32));
    const int total = __popc(b32);
    const int slot  = __popc(b32 & ((1u << r) - 1u));

    if (valid) {
        const float4 P = pos4[nj];          // single 16B transaction
        const float vx = P.x - C.x, vy = P.y - C.y, vz = P.z - C.z;
        const float d2 = fmaf(vx, vx, fmaf(vy, vy, vz * vz));
        const float inv = __builtin_amdgcn_rcpf(sqrtf(d2) + 1e-10f);
        su[al * KNBR + slot] = make_float4(vx * inv, vy * inv, vz * inv, 0.f);
    }
    // writers and readers are the same wave: DS ops execute in program order,
    // no barrier needed (su row is private to this 32-lane group).

    const int npairs = (total * (total - 1)) >> 1;
    const float4* row = &su[al * KNBR];

    float gsum = 0.f, s2 = 0.f, s4 = 0.f, s6 = 0.f;
    for (int p = r; p < npairs; p += GRP) {
        // triangular decode: 8p+1 is an exact perfect square at boundaries
        const int j  = (int)((1.0f + sqrtf(fmaf(8.f, (float)p, 1.0f))) * 0.5f);
        const int ii = p - ((j * (j - 1)) >> 1);

        const float4 A = row[ii];
        const float4 B = row[j];
        const float d = fmaf(A.x, B.x, fmaf(A.y, B.y, A.z * B.z));

        // Legendre sums for q2/q4/q6 (addition theorem)
        const float e = d * d;
        s2 += fmaf(1.5f, e, -0.5f);
        s4 += fmaf(fmaf(4.375f, e, -3.75f), e, 0.375f);
        s6 += fmaf(fmaf(fmaf(14.4375f, e, -19.6875f), e, 6.5625f), e, -0.3125f);

        // tetrahedral gaussian
        float dc = fminf(fmaxf(d, -0.9999999f), 0.9999999f);
        const float ad = fabsf(dc);
        const float pq = fmaf(fmaf(fmaf(-0.0187293f, ad, 0.0742610f), ad, -0.2121144f), ad,
                              1.5707288f) * sqrtf(1.f - ad);
        const float ang = (dc >= 0.f) ? pq : PI_F - pq;
        const float t = (ang - THETA_T) * INV_SIG;
        gsum += __expf(-0.5f * t * t);
    }

#define RED(v) { v += __shfl_xor(v,1); v += __shfl_xor(v,2); v += __shfl_xor(v,4); \
                 v += __shfl_xor(v,8); v += __shfl_xor(v,16); }
    RED(gsum) RED(s2) RED(s4) RED(s6)
#undef RED

    const float cn = (float)total;
    const float invnb = 1.f / fmaxf(cn, 1.f);

    if      (r == 0) out[0 * M + i] = cn;
    else if (r == 1) out[1 * M + i] = 2.f * gsum / fmaxf(cn * (cn - 1.f), 1.f);
    else if (r == 2) out[2 * M + i] = invnb * sqrtf(fmaxf(fmaf(2.f, s2, cn), 0.f));
    else if (r == 3) out[3 * M + i] = invnb * sqrtf(fmaxf(fmaf(2.f, s4, cn), 0.f));
    else if (r == 4) out[4 * M + i] = invnb * sqrtf(fmaxf(fmaf(2.f, s6, cn), 0.f));
}

extern "C" void kernel_launch(void* const* d_in, const int* in_sizes, int n_in,
                              void* d_out, int out_size, void* d_ws, size_t ws_size,
                              hipStream_t stream) {
    const float* pos  = (const float*)d_in[0];
    const int*   aidx = (const int*)d_in[1];
    const int*   nidx = (const int*)d_in[2];
    const int*   vmsk = (const int*)d_in[3];
    float*  out  = (float*)d_out;
    float4* pos4 = (float4*)d_ws;
    const int N = in_sizes[0] / 3;
    const int M = in_sizes[1];

    k_pack<<<(N + BLK - 1) / BLK, BLK, 0, stream>>>(pos, pos4, N);

    const int grid = (M + APB - 1) / APB;
    op_kernel<<<grid, BLK, 0, stream>>>(pos4, aidx, nidx, vmsk, out, M);
}

// Round 8
// 27.239 us; speedup vs baseline: 1.1989x; 1.1989x over previous
//
#include <hip/hip_runtime.h>
#include <math.h>

#define KNBR 20
#define BLK  256
#define GRP  32              // lanes per atom
#define APB  (BLK / GRP)     // 8 atoms per block

#define THETA_T  1.9106332362490186f   // 0.6081734479693927 * pi
#define INV_SIG  4.7746482927568605f   // 1 / (12 deg in rad)
#define PI_F     3.14159265358979323846f

// q_l via the SH addition theorem: q_l = (1/nb)*sqrt(cn + 2*sum_{i<j} P_l(d_ij)).
// Self-neighbor handling (nj == center -> vec = 0): the reference's SH path
// maps it to direction (1,0,0) (theta=pi/2, phi=0) while its pair/tet path
// keeps the zero vector. We store (u_sh, w): zero-entries store (1,0,0) with
// w=0, normal entries (u, 1). Then d_sh = dot3 and d_tet = d_sh * A.w * B.w.
__global__ __launch_bounds__(BLK, 8)
void op_kernel(const float* __restrict__ pos,
               const int*   __restrict__ aidx,
               const int*   __restrict__ nidx,
               const int*   __restrict__ vmsk,
               float*       __restrict__ out,
               int M)
{
    __shared__ float4 su[APB * KNBR];       // 2560 B
    const int tid  = threadIdx.x;
    const int r    = tid & (GRP - 1);       // lane within 32-lane group
    const int al   = tid / GRP;             // atom in block 0..7
    const int i    = blockIdx.x * APB + al;
    if (i >= M) return;
    const int half = (tid & 63) >> 5;       // which 32-half of the wave

    // center position (uniform within group -> broadcast loads)
    const int a = aidx[i];
    const float cx = pos[3 * a], cy = pos[3 * a + 1], cz = pos[3 * a + 2];

    // lane r < 20 owns neighbor slot r
    int valid = 0, nj = 0;
    if (r < KNBR) {
        nj    = nidx[(size_t)i * KNBR + r];
        valid = vmsk[(size_t)i * KNBR + r] != 0;
    }
    const unsigned long long bal = __ballot(valid != 0);
    const unsigned int b32 = (unsigned int)(bal >> (half * 32));
    const int total = __popc(b32);
    const int slot  = __popc(b32 & ((1u << r) - 1u));

    if (valid) {
        const float px = pos[3 * nj], py = pos[3 * nj + 1], pz = pos[3 * nj + 2];
        const float vx = px - cx, vy = py - cy, vz = pz - cz;
        const float d2 = fmaf(vx, vx, fmaf(vy, vy, vz * vz));
        const int   zed = d2 < 1e-24f;                    // self-neighbor
        const float inv = __builtin_amdgcn_rcpf(sqrtf(d2) + 1e-10f);
        const float ux = zed ? 1.f : vx * inv;
        const float uy = zed ? 0.f : vy * inv;
        const float uz = zed ? 0.f : vz * inv;
        su[al * KNBR + slot] = make_float4(ux, uy, uz, zed ? 0.f : 1.f);
    }
    // writers and readers are the same wave: DS ops execute in program order,
    // no barrier needed (su row is private to this 32-lane group).

    const int npairs = (total * (total - 1)) >> 1;
    const float4* row = &su[al * KNBR];

    float gs0 = 0.f, s20 = 0.f, s40 = 0.f, s60 = 0.f;
    float gs1 = 0.f, s21 = 0.f, s41 = 0.f, s61 = 0.f;

#define PAIR_BODY(P, GS, S2, S4, S6)                                          \
    {                                                                          \
        const int j  = (int)((1.0f + sqrtf(fmaf(8.f, (float)(P), 1.0f))) * 0.5f); \
        const int ii = (P) - ((j * (j - 1)) >> 1);                             \
        const float4 A = row[ii];                                              \
        const float4 B = row[j];                                               \
        const float dsh = fmaf(A.x, B.x, fmaf(A.y, B.y, A.z * B.z));           \
        const float dtt = dsh * A.w * B.w;                                     \
        const float e = dsh * dsh;                                             \
        S2 += fmaf(1.5f, e, -0.5f);                                            \
        S4 += fmaf(fmaf(4.375f, e, -3.75f), e, 0.375f);                        \
        S6 += fmaf(fmaf(fmaf(14.4375f, e, -19.6875f), e, 6.5625f), e, -0.3125f); \
        const float dc = fminf(fmaxf(dtt, -0.9999999f), 0.9999999f);           \
        const float ad = fabsf(dc);                                            \
        const float pq = fmaf(fmaf(fmaf(-0.0187293f, ad, 0.0742610f), ad,      \
                              -0.2121144f), ad, 1.5707288f) * sqrtf(1.f - ad); \
        const float ang = (dc >= 0.f) ? pq : PI_F - pq;                        \
        const float t = (ang - THETA_T) * INV_SIG;                             \
        GS += __expf(-0.5f * t * t);                                           \
    }

    for (int p = r; p < npairs; p += 2 * GRP) {
        PAIR_BODY(p, gs0, s20, s40, s60)
        const int p2 = p + GRP;
        if (p2 < npairs)
            PAIR_BODY(p2, gs1, s21, s41, s61)
    }
#undef PAIR_BODY

    float gsum = gs0 + gs1, s2 = s20 + s21, s4 = s40 + s41, s6 = s60 + s61;

#define RED(v) { v += __shfl_xor(v,1); v += __shfl_xor(v,2); v += __shfl_xor(v,4); \
                 v += __shfl_xor(v,8); v += __shfl_xor(v,16); }
    RED(gsum) RED(s2) RED(s4) RED(s6)
#undef RED

    const float cn = (float)total;
    const float invnb = 1.f / fmaxf(cn, 1.f);

    if      (r == 0) out[0 * M + i] = cn;
    else if (r == 1) out[1 * M + i] = 2.f * gsum / fmaxf(cn * (cn - 1.f), 1.f);
    else if (r == 2) out[2 * M + i] = invnb * sqrtf(fmaxf(fmaf(2.f, s2, cn), 0.f));
    else if (r == 3) out[3 * M + i] = invnb * sqrtf(fmaxf(fmaf(2.f, s4, cn), 0.f));
    else if (r == 4) out[4 * M + i] = invnb * sqrtf(fmaxf(fmaf(2.f, s6, cn), 0.f));
}

extern "C" void kernel_launch(void* const* d_in, const int* in_sizes, int n_in,
                              void* d_out, int out_size, void* d_ws, size_t ws_size,
                              hipStream_t stream) {
    const float* pos  = (const float*)d_in[0];
    const int*   aidx = (const int*)d_in[1];
    const int*   nidx = (const int*)d_in[2];
    const int*   vmsk = (const int*)d_in[3];
    float* out = (float*)d_out;
    const int M = in_sizes[1];
    const int grid = (M + APB - 1) / APB;
    op_kernel<<<grid, BLK, 0, stream>>>(pos, aidx, nidx, vmsk, out, M);
}

// Round 9
// 20.925 us; speedup vs baseline: 1.5607x; 1.3018x over previous
//
#include <hip/hip_runtime.h>
#include <math.h>

#define KNBR 20
#define BLK  256
#define GRP  16                 // lanes per atom
#define APB  (BLK / GRP)        // 16 atoms per block-tile
#define MAXP 190                // C(20,2)
#define PERSIST 2048            // 8 blocks/CU * 256 CU

#define THETA_T  1.9106332362490186f   // 0.6081734479693927 * pi
#define INV_SIG  4.7746482927568605f   // 1 / (12 deg in rad)
#define PI_F     3.14159265358979323846f

// Persistent-block kernel. q_l via SH addition theorem:
//   q_l = (1/nb)*sqrt(cn + 2*sum_{i<j} P_l(d_ij)),
// P_l sums tracked as moments m1=Σe, m2=Σe², m3=Σe³ (e = d²).
// Self-neighbors (vec=0): reference SH maps them to (1,0,0), tet keeps 0 —
// stored as (1,0,0,w=0); d_sh = dot3, d_tet = d_sh*A.w*B.w.
__global__ __launch_bounds__(BLK, 8)
void op_kernel(const float* __restrict__ pos,
               const int*   __restrict__ aidx,
               const int*   __restrict__ nidx,
               const int*   __restrict__ vmsk,
               float*       __restrict__ out,
               int M, int NT)
{
    __shared__ float4 su[APB * KNBR];       // 5120 B
    __shared__ unsigned short lut[MAXP];    // 380 B: ii | (j<<8)

    const int tid = threadIdx.x;
    if (tid < MAXP) {
        const int j  = (int)((1.0f + sqrtf(fmaf(8.f, (float)tid, 1.0f))) * 0.5f);
        const int ii = tid - ((j * (j - 1)) >> 1);
        lut[tid] = (unsigned short)(ii | (j << 8));
    }
    __syncthreads();

    const int r   = tid & (GRP - 1);        // lane within 16-lane group
    const int g   = tid / GRP;              // group in block 0..15
    const int sub = (tid & 63) >> 4;        // 16-lane subgroup within wave 0..3
    float4* row = &su[g * KNBR];

    int t = blockIdx.x;
    if (t >= NT) return;

    // ---- stage tile t ----
    int i = t * APB + g;
    int is = min(i, M - 1);
    int a  = aidx[is];
    size_t ri = (size_t)is * KNBR;
    int n0 = nidx[ri + r];
    int v0 = (i < M) ? vmsk[ri + r] : 0;
    int n1 = 0, v1 = 0;
    if (r < 4) { n1 = nidx[ri + 16 + r]; v1 = (i < M) ? vmsk[ri + 16 + r] : 0; }

    while (true) {
        const int tn = t + gridDim.x;
        // ---- prefetch tile tn (hides HBM index latency under compute) ----
        int aN = 0, n0N = 0, v0N = 0, n1N = 0, v1N = 0, iN = 0;
        if (tn < NT) {
            iN = tn * APB + g;
            const int isN = min(iN, M - 1);
            aN = aidx[isN];
            const size_t rN = (size_t)isN * KNBR;
            n0N = nidx[rN + r];
            v0N = (iN < M) ? vmsk[rN + r] : 0;
            if (r < 4) { n1N = nidx[rN + 16 + r]; v1N = (iN < M) ? vmsk[rN + 16 + r] : 0; }
        }

        // ---- compute tile t ----
        const float cx = pos[3*a], cy = pos[3*a+1], cz = pos[3*a+2];
        const int use1 = (r < 4) & (v1 != 0);
        const int s0i = (v0 != 0) ? n0 : 0;
        const int s1i = use1 ? n1 : 0;
        // unconditional gathers (uniform exec, max MLP)
        const float p0x = pos[3*s0i], p0y = pos[3*s0i+1], p0z = pos[3*s0i+2];
        const float p1x = pos[3*s1i], p1y = pos[3*s1i+1], p1z = pos[3*s1i+2];

        const unsigned long long bal0 = __ballot(v0 != 0);
        const unsigned long long bal1 = __ballot(use1 != 0);
        const unsigned int b16 = (unsigned int)(bal0 >> (sub * 16)) & 0xFFFFu;
        const unsigned int c4  = (unsigned int)(bal1 >> (sub * 16)) & 0xFu;
        const unsigned int mask20 = b16 | (c4 << 16);
        const int total = __popc(mask20);

        if (v0 != 0) {
            const float vx = p0x - cx, vy = p0y - cy, vz = p0z - cz;
            const float d2 = fmaf(vx, vx, fmaf(vy, vy, vz * vz));
            const int   zed = d2 < 1e-24f;
            const float inv = __builtin_amdgcn_rcpf(sqrtf(d2) + 1e-10f);
            const int slot = __popc(mask20 & ((1u << r) - 1u));
            row[slot] = make_float4(zed ? 1.f : vx * inv,
                                    zed ? 0.f : vy * inv,
                                    zed ? 0.f : vz * inv,
                                    zed ? 0.f : 1.f);
        }
        if (use1) {
            const float vx = p1x - cx, vy = p1y - cy, vz = p1z - cz;
            const float d2 = fmaf(vx, vx, fmaf(vy, vy, vz * vz));
            const int   zed = d2 < 1e-24f;
            const float inv = __builtin_amdgcn_rcpf(sqrtf(d2) + 1e-10f);
            const int slot = __popc(mask20 & ((1u << (16 + r)) - 1u));
            row[slot] = make_float4(zed ? 1.f : vx * inv,
                                    zed ? 0.f : vy * inv,
                                    zed ? 0.f : vz * inv,
                                    zed ? 0.f : 1.f);
        }
        // writers == readers (same wave): DS program order, no barrier needed.

        const int npairs = (total * (total - 1)) >> 1;
        float m1 = 0.f, m2 = 0.f, m3 = 0.f, gsum = 0.f;
        for (int p = r; p < npairs; p += GRP) {
            const unsigned short w = lut[p];
            const float4 A = row[w & 0xFF];
            const float4 B = row[w >> 8];
            const float dsh = fmaf(A.x, B.x, fmaf(A.y, B.y, A.z * B.z));
            const float dtt = dsh * A.w * B.w;

            const float e  = dsh * dsh;
            const float e2 = e * e;
            m1 += e;
            m2 += e2;
            m3 = fmaf(e2, e, m3);

            const float dc = fminf(fmaxf(dtt, -0.9999999f), 0.9999999f);
            const float ad = fabsf(dc);
            const float pq = fmaf(fmaf(fmaf(-0.0187293f, ad, 0.0742610f), ad,
                                  -0.2121144f), ad, 1.5707288f) * sqrtf(1.f - ad);
            const float ang = (dc >= 0.f) ? pq : PI_F - pq;
            const float tt = (ang - THETA_T) * INV_SIG;
            gsum += __expf(-0.5f * tt * tt);
        }

#define RED(v) { v += __shfl_xor(v,1); v += __shfl_xor(v,2); \
                 v += __shfl_xor(v,4); v += __shfl_xor(v,8); }
        RED(m1) RED(m2) RED(m3) RED(gsum)
#undef RED

        const float fnp = (float)npairs;
        const float s2 = fmaf(1.5f, m1, -0.5f * fnp);
        const float s4 = fmaf(4.375f, m2, fmaf(-3.75f, m1, 0.375f * fnp));
        const float s6 = fmaf(14.4375f, m3,
                         fmaf(-19.6875f, m2, fmaf(6.5625f, m1, -0.3125f * fnp)));

        const float cn = (float)total;
        const float invnb = 1.f / fmaxf(cn, 1.f);
        const float tet = 2.f * gsum / fmaxf(cn * (cn - 1.f), 1.f);
        const float q2v = invnb * sqrtf(fmaxf(fmaf(2.f, s2, cn), 0.f));
        const float q4v = invnb * sqrtf(fmaxf(fmaf(2.f, s4, cn), 0.f));
        const float q6v = invnb * sqrtf(fmaxf(fmaf(2.f, s6, cn), 0.f));

        float val = cn;
        val = (r == 1) ? tet : val;
        val = (r == 2) ? q2v : val;
        val = (r == 3) ? q4v : val;
        val = (r == 4) ? q6v : val;
        if (r < 5 && i < M)
            out[r * M + i] = val;

        if (tn >= NT) break;
        t = tn; i = iN; a = aN;
        n0 = n0N; v0 = v0N; n1 = n1N; v1 = v1N;
    }
}

extern "C" void kernel_launch(void* const* d_in, const int* in_sizes, int n_in,
                              void* d_out, int out_size, void* d_ws, size_t ws_size,
                              hipStream_t stream) {
    const float* pos  = (const float*)d_in[0];
    const int*   aidx = (const int*)d_in[1];
    const int*   nidx = (const int*)d_in[2];
    const int*   vmsk = (const int*)d_in[3];
    float* out = (float*)d_out;
    const int M = in_sizes[1];
    const int NT = (M + APB - 1) / APB;
    const int grid = NT < PERSIST ? NT : PERSIST;
    op_kernel<<<grid, BLK, 0, stream>>>(pos, aidx, nidx, vmsk, out, M, NT);
}